// Round 9
// baseline (320.189 us; speedup 1.0000x reference)
//
#include <hip/hip_runtime.h>
#include <hip/hip_bf16.h>

#define PREFIX_N 20000
#define LEAF_N   50000
#define CH_N     100000
#define CCOL     256
#define GK       2048
#define GM       50000
#define BM       64
#define NKC      16                      /* K chunks of 128 values */
#define TILES    ((GM + BM - 1) / BM)    /* 782 */
#define GA       (GM * 256)              /* A granules (16B bf16) = 12.8M */
#define GC       (70000 * 64)            /* copy float4 items */
#define NBA      1512
#define NBC      528
#define NBW      8

typedef float  f32x4v __attribute__((ext_vector_type(4)));
typedef __bf16 bf16x8 __attribute__((ext_vector_type(8)));
typedef short  s16x8  __attribute__((ext_vector_type(8)));

static __device__ __forceinline__ unsigned pk2(float a, float b) {
  __hip_bfloat16 ha = __float2bfloat16(a);
  __hip_bfloat16 hb = __float2bfloat16(b);
  unsigned short sa = __builtin_bit_cast(unsigned short, ha);
  unsigned short sb = __builtin_bit_cast(unsigned short, hb);
  return (unsigned)sa | ((unsigned)sb << 16);
}
static __device__ __forceinline__ uint4 pack8(const float4& x, const float4& y) {
  uint4 r;
  r.x = pk2(x.x, x.y); r.y = pk2(x.z, x.w);
  r.z = pk2(y.x, y.y); r.w = pk2(y.z, y.w);
  return r;
}

#define GLDS16(g, l) __builtin_amdgcn_global_load_lds(                      \
    (const __attribute__((address_space(1))) void*)(g),                     \
    (__attribute__((address_space(3))) void*)(l), 16, 0, 0)

// ---- rank pipeline (tiny) ------------------------------------------------
__global__ __launch_bounds__(256) void count_leaves(const int* __restrict__ ch,
                                                    int n, int* __restrict__ cnt) {
  int gi = blockIdx.x * 256 + threadIdx.x;
  int lm = (gi < n && ch[gi] < 0) ? 1 : 0;
  unsigned long long mask = __ballot(lm);
  __shared__ int wsum[4];
  int lane = threadIdx.x & 63, w = threadIdx.x >> 6;
  if (lane == 0) wsum[w] = __popcll(mask);
  __syncthreads();
  if (threadIdx.x == 0) cnt[blockIdx.x] = wsum[0] + wsum[1] + wsum[2] + wsum[3];
}

__global__ __launch_bounds__(512) void scan_blocks(const int* __restrict__ cnt,
                                                   int* __restrict__ boff, int nb) {
  __shared__ int s[512];
  int t = threadIdx.x;
  int v = (t < nb) ? cnt[t] : 0;
  s[t] = v;
  __syncthreads();
  for (int d = 1; d < 512; d <<= 1) {
    int add = (t >= d) ? s[t - d] : 0;
    __syncthreads();
    s[t] += add;
    __syncthreads();
  }
  if (t < nb) boff[t] = s[t] - v;
}

__global__ __launch_bounds__(256) void rank_kernel(const int* __restrict__ ch,
                                                   const int* __restrict__ boff, int n,
                                                   int* __restrict__ rowof,
                                                   int* __restrict__ leafof) {
  int gi = blockIdx.x * 256 + threadIdx.x;
  int lane = threadIdx.x & 63, w = threadIdx.x >> 6;
  int lm = (gi < n && ch[gi] < 0) ? 1 : 0;
  unsigned long long mask = __ballot(lm);
  int lrank = __popcll(mask & ((1ull << lane) - 1ull));
  __shared__ int wcnt[4];
  if (lane == 63) wcnt[w] = lrank + lm;
  __syncthreads();
  int woff = 0;
  for (int i = 0; i < w; ++i) woff += wcnt[i];
  if (gi < n) {
    int rl = boff[blockIdx.x] + woff + lrank;
    if (lm) leafof[rl] = gi;
    else    rowof[gi - rl] = gi;
  }
}

// ---- pass 1: fill-like streamer (no LDS, no barriers, 32 waves/CU) -------
// blocks [0,NBA): A fp32 -> bf16, tiled layout Ab[tile][kc][r][g'] with
//   granule swizzle g' = g ^ (R&15) baked at write time (read = linear).
// blocks [NBA,NBA+NBC): prefix+leaf row copies (linear read, row scatter).
// blocks [NBA+NBC,..): W fp32 -> bf16.
__global__ __launch_bounds__(256) void stream_kernel(const float* __restrict__ x,
                                                     const float* __restrict__ A,
                                                     const float* __restrict__ W,
                                                     unsigned short* __restrict__ Wb,
                                                     uint4* __restrict__ Abg,
                                                     const int* __restrict__ leafof,
                                                     float* __restrict__ out) {
  const int tid = threadIdx.x;
  if (blockIdx.x < NBA) {
    const int stride = NBA * 256;
    for (int j = blockIdx.x * 256 + tid; j < GA; j += stride) {
      const float4* ps = (const float4*)A + (size_t)j * 2;   // linear read
      float4 v0 = ps[0], v1 = ps[1];
      int R = j >> 8, q = j & 255;                           // GEMM row, granule
      int kc = q >> 4, g = q & 15;
      int gs = g ^ (R & 15);                                 // baked swizzle
      size_t dgi = (((size_t)(R >> 6) * NKC + kc) * BM + (R & 63)) * 16 + gs;
      Abg[dgi] = pack8(v0, v1);
    }
  } else if (blockIdx.x < NBA + NBC) {
    const int stride = NBC * 256;
    for (int c = (blockIdx.x - NBA) * 256 + tid; c < GC; c += stride) {
      int row = c >> 6, col = c & 63;
      int drow = (row < PREFIX_N) ? row : (PREFIX_N + leafof[row - PREFIX_N]);
      ((float4*)out)[(size_t)drow * 64 + col] =
          ((const float4*)x)[(size_t)row * 64 + col];
    }
  } else {
    const int stride = NBW * 256;
    for (int i = (blockIdx.x - NBA - NBC) * 256 + tid; i < 65536; i += stride) {
      float4 a = ((const float4*)W)[i * 2];
      float4 b = ((const float4*)W)[i * 2 + 1];
      *(uint4*)&Wb[i * 8] = pack8(a, b);
    }
  }
}

// ---- pass 2: GEMM on tiled bf16 A (L3-resident) --------------------------
// BM=64, BN=256(full), chunk=128 K-values; 256 thr = 4 waves (N-split),
// wave-tile 64x64. A via global_load_lds from the tiled buffer: per block
// the A-stream is one LINEAR 256KB region. dbuf LDS (2x16KB), counted
// vmcnt, raw barriers. B direct from L2-resident bf16 W.
__global__ __launch_bounds__(256, 3) void gemm_kernel(const uint4* __restrict__ Abg,
                                                      const unsigned short* __restrict__ Wb,
                                                      const int* __restrict__ rowof,
                                                      float* __restrict__ out) {
  __shared__ char Al[2][16384];
  __shared__ int tgt[BM];

  const int tid  = threadIdx.x;
  const int lane = tid & 63;
  const int w    = tid >> 6;          // wave = N-quadrant
  const int lr   = lane & 15, lq = lane >> 4;
  const int tile = blockIdx.x;

  if (tid < BM) {
    int m = tile * BM + tid;
    tgt[tid] = (m < GM) ? (PREFIX_N + rowof[m]) : -1;
  }

  // linear glds source: tile base + kc*16KB + (w*4+i)*1KB + lane*16
  const char* src0 = (const char*)(Abg + (size_t)tile * (NKC * BM * 16))
                     + w * 4096 + lane * 16;

  const unsigned short* bb[4];
#pragma unroll
  for (int fn = 0; fn < 4; ++fn)
    bb[fn] = Wb + (size_t)(w * 64 + fn * 16 + lr) * GK + lq * 8;

  f32x4v acc[4][4] = {};

#define ISSUE(kc_, buf_)                                                     \
  { _Pragma("unroll") for (int i = 0; i < 4; ++i)                            \
      GLDS16(src0 + (kc_) * 16384 + i * 1024, &Al[(buf_)][(w * 4 + i) * 1024]); }

  ISSUE(0, 0);
  ISSUE(1, 1);

#pragma unroll 1
  for (int kc = 0; kc < NKC; ++kc) {
    if (kc < NKC - 1) { asm volatile("s_waitcnt vmcnt(4)" ::: "memory"); }
    else              { asm volatile("s_waitcnt vmcnt(0)" ::: "memory"); }
    __builtin_amdgcn_s_barrier();                 // buf kc staged (all waves)

    const char* Ab = Al[kc & 1];
#pragma unroll
    for (int ks = 0; ks < 4; ++ks) {
      s16x8 af[4], bf[4];
#pragma unroll
      for (int fm = 0; fm < 4; ++fm)
        af[fm] = *(const s16x8*)(Ab + (fm * 16 + lr) * 256 +
                                 (((ks * 4 + lq) ^ lr) << 4));
#pragma unroll
      for (int fn = 0; fn < 4; ++fn)
        bf[fn] = *(const s16x8*)&bb[fn][kc * 128 + ks * 32];
#pragma unroll
      for (int fm = 0; fm < 4; ++fm)
#pragma unroll
        for (int fn = 0; fn < 4; ++fn)
          acc[fm][fn] = __builtin_amdgcn_mfma_f32_16x16x32_bf16(
              __builtin_bit_cast(bf16x8, af[fm]),
              __builtin_bit_cast(bf16x8, bf[fn]),
              acc[fm][fn], 0, 0, 0);
    }

    asm volatile("s_waitcnt lgkmcnt(0)" ::: "memory");  // frag reads done
    __builtin_amdgcn_s_barrier();                       // safe to overwrite
    if (kc + 2 < NKC) ISSUE(kc + 2, kc & 1);
  }
#undef ISSUE

  // ---- epilogue: scatter rows (C/D: col=lane&15, row=(lane>>4)*4+reg) ----
#pragma unroll
  for (int fm = 0; fm < 4; ++fm) {
    int mlb = fm * 16 + lq * 4;
    int t0 = tgt[mlb + 0], t1 = tgt[mlb + 1], t2 = tgt[mlb + 2], t3 = tgt[mlb + 3];
#pragma unroll
    for (int fn = 0; fn < 4; ++fn) {
      int col = w * 64 + fn * 16 + lr;
      if (t0 >= 0) out[(size_t)t0 * CCOL + col] = acc[fm][fn][0];
      if (t1 >= 0) out[(size_t)t1 * CCOL + col] = acc[fm][fn][1];
      if (t2 >= 0) out[(size_t)t2 * CCOL + col] = acc[fm][fn][2];
      if (t3 >= 0) out[(size_t)t3 * CCOL + col] = acc[fm][fn][3];
    }
  }
}

extern "C" void kernel_launch(void* const* d_in, const int* in_sizes, int n_in,
                              void* d_out, int out_size, void* d_ws, size_t ws_size,
                              hipStream_t stream) {
  const float* x        = (const float*)d_in[0];
  const float* wts      = (const float*)d_in[1];   // (256,256,8) == row-major (256,2048)
  const int*   children = (const int*)d_in[2];
  float*       out      = (float*)d_out;

  int* wsp    = (int*)d_ws;
  int* cnt    = wsp;                 // 391
  int* boff   = wsp + 512;           // 391
  int* rowof  = wsp + 1024;          // 50000
  int* leafof = wsp + 1024 + GM;     // 50000
  unsigned short* Wb = (unsigned short*)((char*)d_ws + (1 << 20));   // 1 MB
  uint4* Abg = (uint4*)((char*)d_ws + (2u << 20));   // 200.2 MB tiled bf16 A

  const int nb = (CH_N + 255) / 256;   // 391

  count_leaves<<<nb, 256, 0, stream>>>(children, CH_N, cnt);
  scan_blocks<<<1, 512, 0, stream>>>(cnt, boff, nb);
  rank_kernel<<<nb, 256, 0, stream>>>(children, boff, CH_N, rowof, leafof);

  const float* A = x + (size_t)(PREFIX_N + LEAF_N) * CCOL;
  stream_kernel<<<NBA + NBC + NBW, 256, 0, stream>>>(x, A, wts, Wb, Abg,
                                                     leafof, out);
  gemm_kernel<<<TILES, 256, 0, stream>>>(Abg, Wb, rowof, out);
}

// Round 10
// 239.005 us; speedup vs baseline: 1.3397x; 1.3397x over previous
//
#include <hip/hip_runtime.h>
#include <hip/hip_bf16.h>

#define PREFIX_N 20000
#define LEAF_N   50000
#define CH_N     100000
#define CCOL     256
#define GK       2048
#define GM       50000
#define BM       64
#define BKF      64                     /* K floats per step */
#define NSTP     (GK / BKF)             /* 32 steps */
#define TILES    ((GM + BM - 1) / BM)   /* 782 */
#define NCOPYB   242                    /* 782+242 = 1024 = one full round */
#define COPYROWS 70000

typedef float  f32x4v __attribute__((ext_vector_type(4)));
typedef __bf16 bf16x8 __attribute__((ext_vector_type(8)));
typedef short  s16x8  __attribute__((ext_vector_type(8)));

static __device__ __forceinline__ unsigned pk2(float a, float b) {
  __hip_bfloat16 ha = __float2bfloat16(a);
  __hip_bfloat16 hb = __float2bfloat16(b);
  unsigned short sa = __builtin_bit_cast(unsigned short, ha);
  unsigned short sb = __builtin_bit_cast(unsigned short, hb);
  return (unsigned)sa | ((unsigned)sb << 16);
}
static __device__ __forceinline__ uint4 pack8(const float4& x, const float4& y) {
  uint4 r;
  r.x = pk2(x.x, x.y); r.y = pk2(x.z, x.w);
  r.z = pk2(y.x, y.y); r.w = pk2(y.z, y.w);
  return r;
}

#define GLDS16(g, l) __builtin_amdgcn_global_load_lds(                      \
    (const __attribute__((address_space(1))) void*)(g),                     \
    (__attribute__((address_space(3))) void*)(l), 16, 0, 0)

// ---- prep: W fp32->bf16 (blocks 0..255) + leaf count (blocks 256..646) ---
__global__ __launch_bounds__(256) void prep_kernel(const float* __restrict__ W,
                                                   unsigned short* __restrict__ Wb,
                                                   const int* __restrict__ ch,
                                                   int* __restrict__ cnt) {
  if (blockIdx.x < 256) {
    int i = blockIdx.x * 256 + threadIdx.x;
    float4 a = ((const float4*)W)[i * 2];
    float4 b = ((const float4*)W)[i * 2 + 1];
    *(uint4*)&Wb[i * 8] = pack8(a, b);
  } else {
    int blk = blockIdx.x - 256;
    int gi = blk * 256 + threadIdx.x;
    int lm = (gi < CH_N && ch[gi] < 0) ? 1 : 0;
    unsigned long long mask = __ballot(lm);
    __shared__ int wsum[4];
    int lane = threadIdx.x & 63, w = threadIdx.x >> 6;
    if (lane == 0) wsum[w] = __popcll(mask);
    __syncthreads();
    if (threadIdx.x == 0) cnt[blk] = wsum[0] + wsum[1] + wsum[2] + wsum[3];
  }
}

__global__ __launch_bounds__(512) void scan_blocks(const int* __restrict__ cnt,
                                                   int* __restrict__ boff, int nb) {
  __shared__ int s[512];
  int t = threadIdx.x;
  int v = (t < nb) ? cnt[t] : 0;
  s[t] = v;
  __syncthreads();
  for (int d = 1; d < 512; d <<= 1) {
    int add = (t >= d) ? s[t - d] : 0;
    __syncthreads();
    s[t] += add;
    __syncthreads();
  }
  if (t < nb) boff[t] = s[t] - v;
}

__global__ __launch_bounds__(256) void rank_kernel(const int* __restrict__ ch,
                                                   const int* __restrict__ boff, int n,
                                                   int* __restrict__ rowof,
                                                   int* __restrict__ leafof) {
  int gi = blockIdx.x * 256 + threadIdx.x;
  int lane = threadIdx.x & 63, w = threadIdx.x >> 6;
  int lm = (gi < n && ch[gi] < 0) ? 1 : 0;
  unsigned long long mask = __ballot(lm);
  int lrank = __popcll(mask & ((1ull << lane) - 1ull));
  __shared__ int wcnt[4];
  if (lane == 63) wcnt[w] = lrank + lm;
  __syncthreads();
  int woff = 0;
  for (int i = 0; i < w; ++i) woff += wcnt[i];
  if (gi < n) {
    int rl = boff[blockIdx.x] + woff + lrank;
    if (lm) leafof[rl] = gi;
    else    rowof[gi - rl] = gi;
  }
}

// ---- main: GEMM tiles (blocks < TILES) + grid-stride row copies ----------
// v6 structure at single-round residency: BM=64, BN=256(full), BK=64;
// 256 thr = 4 waves (N-split); A via global_load_lds (16-granule XOR
// swizzle baked into per-lane source, swizzled frag read), dbuf 2x16KB,
// counted vmcnt(4), raw barriers; B direct from L2-resident bf16 W.
// 4 blocks/CU -> 1024 slots: all 782 tiles + 242 copy blocks in ONE round.
__global__ __launch_bounds__(256, 4) void main_kernel(const float* __restrict__ x,
                                                      const float* __restrict__ A,
                                                      const unsigned short* __restrict__ Wb,
                                                      const int* __restrict__ rowof,
                                                      const int* __restrict__ leafof,
                                                      float* __restrict__ out) {
  __shared__ float Al[2][BM * BKF];    // 2 x 16KB fp32, 16B-granule swizzle
  __shared__ int tgt[BM];

  const int tid  = threadIdx.x;
  const int lane = tid & 63;
  const int w    = tid >> 6;

  if (blockIdx.x >= TILES) {                      // ---- copy path ----
    int cb = blockIdx.x - TILES;
    for (int r0 = cb * 4; r0 < COPYROWS; r0 += NCOPYB * 4) {
      int j = r0 + w;
      if (j >= COPYROWS) break;
      const float* src;
      float* dst;
      if (j < PREFIX_N) {
        src = x + (size_t)j * CCOL;
        dst = out + (size_t)j * CCOL;
      } else {
        int r = j - PREFIX_N;
        src = x + (size_t)(PREFIX_N + r) * CCOL;
        dst = out + (size_t)(PREFIX_N + leafof[r]) * CCOL;
      }
      ((float4*)dst)[lane] = ((const float4*)src)[lane];
    }
    return;
  }

  // ---- GEMM path ----
  const int tile  = blockIdx.x;
  const int phase = tile & (NSTP - 1);
  const int wn    = w;                 // wave's N-quadrant
  const int lr    = lane & 15, lq = lane >> 4;

  if (tid < BM) {
    int m = tile * BM + tid;
    tgt[tid] = (m < GM) ? (PREFIX_N + rowof[m]) : -1;
  }

  // glds i (i=0..3): rows w*16+i*4+(lane>>4); lane granule gs=lane&15 holds
  // global granule gs ^ (localrow & 15)  (inverse swizzle on SOURCE).
  const char* asrc[4];
  int ldsoff[4];
#pragma unroll
  for (int i = 0; i < 4; ++i) {
    int r  = w * 16 + i * 4 + (lane >> 4);        // local row 0..63
    int gr = tile * BM + r;
    if (gr >= GM) gr = GM - 1;                    // clamp (stores predicated)
    int g  = (lane & 15) ^ (r & 15);              // source granule
    asrc[i]   = (const char*)A + (size_t)gr * (GK * 4) + g * 16;
    ldsoff[i] = (w * 16 + i * 4) * (BKF * 4);     // byte base (linear dest)
  }

  // B fragment base pointers (global; Wb 1MB, L2-resident)
  const unsigned short* bb[4];
#pragma unroll
  for (int fn = 0; fn < 4; ++fn)
    bb[fn] = Wb + (size_t)(wn * 64 + fn * 16 + lr) * GK + lq * 8;

  f32x4v acc[4][4] = {};

#define ISSUE_A(kc_, buf_)                                                   \
  { _Pragma("unroll") for (int i = 0; i < 4; ++i)                            \
      GLDS16(asrc[i] + (kc_) * (BKF * 4), (char*)&Al[(buf_)][0] + ldsoff[i]); }

  {
    int kc0 = phase;
    int kc1 = (phase + 1) & (NSTP - 1);
    ISSUE_A(kc0, 0);
    ISSUE_A(kc1, 1);
  }

#pragma unroll 1
  for (int kt = 0; kt < NSTP; ++kt) {
    int kc = phase + kt; if (kc >= NSTP) kc -= NSTP;   // rotated K-chunk
    if (kt < NSTP - 1) { asm volatile("s_waitcnt vmcnt(4)" ::: "memory"); }
    else               { asm volatile("s_waitcnt vmcnt(0)" ::: "memory"); }
    __builtin_amdgcn_s_barrier();      // buf kt fully staged (all waves)

    const float* Ab = &Al[kt & 1][0];
#pragma unroll
    for (int ks = 0; ks < 2; ++ks) {
      s16x8 af[4], bf[4];
#pragma unroll
      for (int fm = 0; fm < 4; ++fm) {
        int row = fm * 16 + lr;
        int e   = ks * 8 + lq * 2;
        int p0  = ((e)     ^ (row & 15)) << 2;    // swizzled granule read
        int p1  = ((e + 1) ^ (row & 15)) << 2;
        float4 u0 = *(const float4*)&Ab[row * BKF + p0];
        float4 u1 = *(const float4*)&Ab[row * BKF + p1];
        af[fm] = __builtin_bit_cast(s16x8, pack8(u0, u1));
      }
#pragma unroll
      for (int fn = 0; fn < 4; ++fn)
        bf[fn] = *(const s16x8*)&bb[fn][kc * BKF + ks * 32];
#pragma unroll
      for (int fm = 0; fm < 4; ++fm)
#pragma unroll
        for (int fn = 0; fn < 4; ++fn)
          acc[fm][fn] = __builtin_amdgcn_mfma_f32_16x16x32_bf16(
              __builtin_bit_cast(bf16x8, af[fm]),
              __builtin_bit_cast(bf16x8, bf[fn]),
              acc[fm][fn], 0, 0, 0);
    }

    asm volatile("s_waitcnt lgkmcnt(0)" ::: "memory");  // frag reads done
    __builtin_amdgcn_s_barrier();                       // safe to overwrite
    if (kt + 2 < NSTP) {
      int kc2 = phase + kt + 2; if (kc2 >= NSTP) kc2 -= NSTP;
      ISSUE_A(kc2, kt & 1);                             // refill just-read buf
    }
  }
#undef ISSUE_A

  // ---- epilogue: scatter rows (C/D: col=lane&15, row=(lane>>4)*4+reg) ----
#pragma unroll
  for (int fm = 0; fm < 4; ++fm) {
    int mlb = fm * 16 + lq * 4;
    int t0 = tgt[mlb + 0], t1 = tgt[mlb + 1], t2 = tgt[mlb + 2], t3 = tgt[mlb + 3];
#pragma unroll
    for (int fn = 0; fn < 4; ++fn) {
      int col = wn * 64 + fn * 16 + lr;
      if (t0 >= 0) out[(size_t)t0 * CCOL + col] = acc[fm][fn][0];
      if (t1 >= 0) out[(size_t)t1 * CCOL + col] = acc[fm][fn][1];
      if (t2 >= 0) out[(size_t)t2 * CCOL + col] = acc[fm][fn][2];
      if (t3 >= 0) out[(size_t)t3 * CCOL + col] = acc[fm][fn][3];
    }
  }
}

extern "C" void kernel_launch(void* const* d_in, const int* in_sizes, int n_in,
                              void* d_out, int out_size, void* d_ws, size_t ws_size,
                              hipStream_t stream) {
  const float* x        = (const float*)d_in[0];
  const float* wts      = (const float*)d_in[1];   // (256,256,8) == row-major (256,2048)
  const int*   children = (const int*)d_in[2];
  float*       out      = (float*)d_out;

  int* wsp    = (int*)d_ws;
  int* cnt    = wsp;                 // 391
  int* boff   = wsp + 512;           // 391
  int* rowof  = wsp + 1024;          // 50000
  int* leafof = wsp + 1024 + GM;     // 50000
  unsigned short* Wb = (unsigned short*)((char*)d_ws + (1 << 20));  // 1 MB bf16 W

  const int nb = (CH_N + 255) / 256;   // 391

  prep_kernel<<<256 + nb, 256, 0, stream>>>(wts, Wb, children, cnt);
  scan_blocks<<<1, 512, 0, stream>>>(cnt, boff, nb);
  rank_kernel<<<nb, 256, 0, stream>>>(children, boff, CH_N, rowof, leafof);

  const float* A = x + (size_t)(PREFIX_N + LEAF_N) * CCOL;
  main_kernel<<<TILES + NCOPYB, 256, 0, stream>>>(x, A, Wb, rowof, leafof, out);
}

// Round 12
// 197.816 us; speedup vs baseline: 1.6186x; 1.2082x over previous
//
#include <hip/hip_runtime.h>
#include <hip/hip_bf16.h>

#define PREFIX_N 20000
#define LEAF_N   50000
#define CH_N     100000
#define CCOL     256
#define GK       2048
#define GM       50000
#define BM       64
#define BKF      128                    /* K floats per step */
#define NST      (GK / BKF)             /* 16 steps */
#define TILES    ((GM + BM - 1) / BM)   /* 782 */
#define NCOPYB   512
#define COPYROWS 70000

typedef float  f32x4v __attribute__((ext_vector_type(4)));
typedef __bf16 bf16x8 __attribute__((ext_vector_type(8)));
typedef short  s16x8  __attribute__((ext_vector_type(8)));

static __device__ __forceinline__ unsigned pk2(float a, float b) {
  __hip_bfloat16 ha = __float2bfloat16(a);
  __hip_bfloat16 hb = __float2bfloat16(b);
  unsigned short sa = __builtin_bit_cast(unsigned short, ha);
  unsigned short sb = __builtin_bit_cast(unsigned short, hb);
  return (unsigned)sa | ((unsigned)sb << 16);
}
static __device__ __forceinline__ uint4 pack8(const float4& x, const float4& y) {
  uint4 r;
  r.x = pk2(x.x, x.y); r.y = pk2(x.z, x.w);
  r.z = pk2(y.x, y.y); r.w = pk2(y.z, y.w);
  return r;
}

// global_load_lds with NT cache policy (aux=2 on gfx940+): A is a
// stream-once operand; don't let it evict Wb/L2-resident lines.
#define GLDS16NT(g, l) __builtin_amdgcn_global_load_lds(                    \
    (const __attribute__((address_space(1))) void*)(g),                     \
    (__attribute__((address_space(3))) void*)(l), 16, 0, 2)

// ---- prep: W fp32->bf16 (blocks 0..255) + leaf count (blocks 256..646) ---
__global__ __launch_bounds__(256) void prep_kernel(const float* __restrict__ W,
                                                   unsigned short* __restrict__ Wb,
                                                   const int* __restrict__ ch,
                                                   int* __restrict__ cnt) {
  if (blockIdx.x < 256) {
    int i = blockIdx.x * 256 + threadIdx.x;
    float4 a = ((const float4*)W)[i * 2];
    float4 b = ((const float4*)W)[i * 2 + 1];
    *(uint4*)&Wb[i * 8] = pack8(a, b);
  } else {
    int blk = blockIdx.x - 256;
    int gi = blk * 256 + threadIdx.x;
    int lm = (gi < CH_N && ch[gi] < 0) ? 1 : 0;
    unsigned long long mask = __ballot(lm);
    __shared__ int wsum[4];
    int lane = threadIdx.x & 63, w = threadIdx.x >> 6;
    if (lane == 0) wsum[w] = __popcll(mask);
    __syncthreads();
    if (threadIdx.x == 0) cnt[blk] = wsum[0] + wsum[1] + wsum[2] + wsum[3];
  }
}

__global__ __launch_bounds__(512) void scan_blocks(const int* __restrict__ cnt,
                                                   int* __restrict__ boff, int nb) {
  __shared__ int s[512];
  int t = threadIdx.x;
  int v = (t < nb) ? cnt[t] : 0;
  s[t] = v;
  __syncthreads();
  for (int d = 1; d < 512; d <<= 1) {
    int add = (t >= d) ? s[t - d] : 0;
    __syncthreads();
    s[t] += add;
    __syncthreads();
  }
  if (t < nb) boff[t] = s[t] - v;
}

__global__ __launch_bounds__(256) void rank_kernel(const int* __restrict__ ch,
                                                   const int* __restrict__ boff, int n,
                                                   int* __restrict__ rowof,
                                                   int* __restrict__ leafof) {
  int gi = blockIdx.x * 256 + threadIdx.x;
  int lane = threadIdx.x & 63, w = threadIdx.x >> 6;
  int lm = (gi < n && ch[gi] < 0) ? 1 : 0;
  unsigned long long mask = __ballot(lm);
  int lrank = __popcll(mask & ((1ull << lane) - 1ull));
  __shared__ int wcnt[4];
  if (lane == 63) wcnt[w] = lrank + lm;
  __syncthreads();
  int woff = 0;
  for (int i = 0; i < w; ++i) woff += wcnt[i];
  if (gi < n) {
    int rl = boff[blockIdx.x] + woff + lrank;
    if (lm) leafof[rl] = gi;
    else    rowof[gi - rl] = gi;
  }
}

// ---- main: GEMM tiles (blocks < TILES) + grid-stride row copies ----------
// Round-6 champion structure, unchanged: BM=64, BN=256(full), BK=128;
// 256 thr = 4 waves (N-split), 2 blk/CU; A via global_load_lds (XOR-
// swizzled source + swizzled frag read), dbuf, counted vmcnt(8), raw
// barriers, per-block K-phase rotation; B direct from L2-resident bf16 W.
// NEW vs round 6: NT cache policy on A stream + NT copy/epilogue traffic.
__global__ __launch_bounds__(256, 2) void main_kernel(const float* __restrict__ x,
                                                      const float* __restrict__ A,
                                                      const unsigned short* __restrict__ Wb,
                                                      const int* __restrict__ rowof,
                                                      const int* __restrict__ leafof,
                                                      float* __restrict__ out) {
  __shared__ float Al[2][BM][BKF];     // 2 x 32KB
  __shared__ int tgt[BM];

  const int tid  = threadIdx.x;
  const int lane = tid & 63;
  const int w    = tid >> 6;

  if (blockIdx.x >= TILES) {                      // ---- copy path ----
    int cb = blockIdx.x - TILES;
    for (int r0 = cb * 4; r0 < COPYROWS; r0 += NCOPYB * 4) {
      int j = r0 + w;
      if (j >= COPYROWS) break;
      const float* src;
      float* dst;
      if (j < PREFIX_N) {
        src = x + (size_t)j * CCOL;
        dst = out + (size_t)j * CCOL;
      } else {
        int r = j - PREFIX_N;
        src = x + (size_t)(PREFIX_N + r) * CCOL;
        dst = out + (size_t)(PREFIX_N + leafof[r]) * CCOL;
      }
      f32x4v v = __builtin_nontemporal_load((const f32x4v*)src + lane);
      __builtin_nontemporal_store(v, (f32x4v*)dst + lane);
    }
    return;
  }

  // ---- GEMM path ----
  const int tile  = blockIdx.x;
  const int phase = tile & (NST - 1);
  const int wn    = w;                 // wave's N-quadrant
  const int lr    = lane & 15, lq = lane >> 4;

  if (tid < BM) {
    int m = tile * BM + tid;
    tgt[tid] = (m < GM) ? (PREFIX_N + rowof[m]) : -1;
  }

  // glds i covers rows w*16+2i (+1 for lanes>=32); source chunk pre-swizzled
  const float* asrc[8];
  int myrow = w * 16 + (lane >> 5);
#pragma unroll
  for (int i = 0; i < 8; ++i) {
    int r  = myrow + 2 * i;            // this lane's global A-row for glds i
    int gr = tile * BM + r;
    if (gr >= GM) gr = GM - 1;         // clamp (epilogue predicated)
    int chunk = (lane & 31) ^ (r & 7); // inverse swizzle on SOURCE
    asrc[i] = A + (size_t)gr * GK + chunk * 4;
  }

  // B fragment base pointers (global; Wb 1MB, L2-resident)
  const unsigned short* bb[4];
#pragma unroll
  for (int fn = 0; fn < 4; ++fn)
    bb[fn] = Wb + (size_t)(wn * 64 + fn * 16 + lr) * GK + lq * 8;

  f32x4v acc[4][4] = {};

#define ISSUE_A(kc_, buf_)                                                   \
  { _Pragma("unroll") for (int i = 0; i < 8; ++i)                            \
      GLDS16NT(asrc[i] + (kc_) * BKF, (char*)&Al[(buf_)][w * 16 + 2 * i][0]); }

  {
    int kc0 = phase;
    int kc1 = (phase + 1) & (NST - 1);
    ISSUE_A(kc0, 0);
    ISSUE_A(kc1, 1);
  }

#pragma unroll 1
  for (int kt = 0; kt < NST; ++kt) {
    int kc = phase + kt; if (kc >= NST) kc -= NST;   // rotated K-chunk
    if (kt < NST - 1) { asm volatile("s_waitcnt vmcnt(8)" ::: "memory"); }
    else              { asm volatile("s_waitcnt vmcnt(0)" ::: "memory"); }
    __builtin_amdgcn_s_barrier();      // buf kt fully staged (all waves)

    const float* Ab = &Al[kt & 1][0][0];
#pragma unroll
    for (int ks = 0; ks < 4; ++ks) {
      s16x8 af[4], bf[4];
#pragma unroll
      for (int fm = 0; fm < 4; ++fm) {
        int row = fm * 16 + lr;
        int e   = ks * 8 + lq * 2;
        int p0  = ((e)     ^ (row & 7)) << 2;   // swizzled read
        int p1  = ((e + 1) ^ (row & 7)) << 2;
        float4 u0 = *(const float4*)&Ab[row * BKF + p0];
        float4 u1 = *(const float4*)&Ab[row * BKF + p1];
        af[fm] = __builtin_bit_cast(s16x8, pack8(u0, u1));
      }
#pragma unroll
      for (int fn = 0; fn < 4; ++fn)
        bf[fn] = *(const s16x8*)&bb[fn][kc * BKF + ks * 32];
#pragma unroll
      for (int fm = 0; fm < 4; ++fm)
#pragma unroll
        for (int fn = 0; fn < 4; ++fn)
          acc[fm][fn] = __builtin_amdgcn_mfma_f32_16x16x32_bf16(
              __builtin_bit_cast(bf16x8, af[fm]),
              __builtin_bit_cast(bf16x8, bf[fn]),
              acc[fm][fn], 0, 0, 0);
    }

    asm volatile("s_waitcnt lgkmcnt(0)" ::: "memory");  // ds_reads of buf kt done
    __builtin_amdgcn_s_barrier();                       // safe to overwrite
    if (kt + 2 < NST) {
      int kc2 = phase + kt + 2; if (kc2 >= NST) kc2 -= NST;
      ISSUE_A(kc2, kt & 1);                             // refill just-read buffer
    }
  }
#undef ISSUE_A

  // ---- epilogue: scatter rows (C/D: col=lane&15, row=(lane>>4)*4+reg) ----
#pragma unroll
  for (int fm = 0; fm < 4; ++fm) {
    int mlb = fm * 16 + lq * 4;
    int t0 = tgt[mlb + 0], t1 = tgt[mlb + 1], t2 = tgt[mlb + 2], t3 = tgt[mlb + 3];
#pragma unroll
    for (int fn = 0; fn < 4; ++fn) {
      int col = wn * 64 + fn * 16 + lr;
      if (t0 >= 0) __builtin_nontemporal_store(acc[fm][fn][0], &out[(size_t)t0 * CCOL + col]);
      if (t1 >= 0) __builtin_nontemporal_store(acc[fm][fn][1], &out[(size_t)t1 * CCOL + col]);
      if (t2 >= 0) __builtin_nontemporal_store(acc[fm][fn][2], &out[(size_t)t2 * CCOL + col]);
      if (t3 >= 0) __builtin_nontemporal_store(acc[fm][fn][3], &out[(size_t)t3 * CCOL + col]);
    }
  }
}

extern "C" void kernel_launch(void* const* d_in, const int* in_sizes, int n_in,
                              void* d_out, int out_size, void* d_ws, size_t ws_size,
                              hipStream_t stream) {
  const float* x        = (const float*)d_in[0];
  const float* wts      = (const float*)d_in[1];   // (256,256,8) == row-major (256,2048)
  const int*   children = (const int*)d_in[2];
  float*       out      = (float*)d_out;

  int* wsp    = (int*)d_ws;
  int* cnt    = wsp;                 // 391
  int* boff   = wsp + 512;           // 391
  int* rowof  = wsp + 1024;          // 50000
  int* leafof = wsp + 1024 + GM;     // 50000
  unsigned short* Wb = (unsigned short*)((char*)d_ws + (1 << 20));  // 1 MB bf16 W

  const int nb = (CH_N + 255) / 256;   // 391

  prep_kernel<<<256 + nb, 256, 0, stream>>>(wts, Wb, children, cnt);
  scan_blocks<<<1, 512, 0, stream>>>(cnt, boff, nb);
  rank_kernel<<<nb, 256, 0, stream>>>(children, boff, CH_N, rowof, leafof);

  const float* A = x + (size_t)(PREFIX_N + LEAF_N) * CCOL;
  main_kernel<<<TILES + NCOPYB, 256, 0, stream>>>(x, A, Wb, rowof, leafof, out);
}

// Round 13
// 196.707 us; speedup vs baseline: 1.6277x; 1.0056x over previous
//
#include <hip/hip_runtime.h>
#include <hip/hip_bf16.h>

#define PREFIX_N 20000
#define LEAF_N   50000
#define CH_N     100000
#define CCOL     256
#define GK       2048
#define GM       50000
#define BM       64
#define BKF      128                    /* K floats per step */
#define NST      (GK / BKF)             /* 16 steps */
#define TILES    ((GM + BM - 1) / BM)   /* 782 */
#define NCOPYB   512
#define COPYROWS 70000

typedef float  f32x4v __attribute__((ext_vector_type(4)));
typedef __bf16 bf16x8 __attribute__((ext_vector_type(8)));
typedef short  s16x8  __attribute__((ext_vector_type(8)));

static __device__ __forceinline__ unsigned pk2(float a, float b) {
  __hip_bfloat16 ha = __float2bfloat16(a);
  __hip_bfloat16 hb = __float2bfloat16(b);
  unsigned short sa = __builtin_bit_cast(unsigned short, ha);
  unsigned short sb = __builtin_bit_cast(unsigned short, hb);
  return (unsigned)sa | ((unsigned)sb << 16);
}
static __device__ __forceinline__ uint4 pack8(const float4& x, const float4& y) {
  uint4 r;
  r.x = pk2(x.x, x.y); r.y = pk2(x.z, x.w);
  r.z = pk2(y.x, y.y); r.w = pk2(y.z, y.w);
  return r;
}

// global_load_lds with NT cache policy (aux=2 on gfx940+): A is a
// stream-once operand; don't let it evict Wb/L2-resident lines.
#define GLDS16NT(g, l) __builtin_amdgcn_global_load_lds(                    \
    (const __attribute__((address_space(1))) void*)(g),                     \
    (__attribute__((address_space(3))) void*)(l), 16, 0, 2)

// ---- prep: W fp32->bf16 (blocks 0..255) + leaf count (blocks 256..646) ---
__global__ __launch_bounds__(256) void prep_kernel(const float* __restrict__ W,
                                                   unsigned short* __restrict__ Wb,
                                                   const int* __restrict__ ch,
                                                   int* __restrict__ cnt) {
  if (blockIdx.x < 256) {
    int i = blockIdx.x * 256 + threadIdx.x;
    float4 a = ((const float4*)W)[i * 2];
    float4 b = ((const float4*)W)[i * 2 + 1];
    *(uint4*)&Wb[i * 8] = pack8(a, b);
  } else {
    int blk = blockIdx.x - 256;
    int gi = blk * 256 + threadIdx.x;
    int lm = (gi < CH_N && ch[gi] < 0) ? 1 : 0;
    unsigned long long mask = __ballot(lm);
    __shared__ int wsum[4];
    int lane = threadIdx.x & 63, w = threadIdx.x >> 6;
    if (lane == 0) wsum[w] = __popcll(mask);
    __syncthreads();
    if (threadIdx.x == 0) cnt[blk] = wsum[0] + wsum[1] + wsum[2] + wsum[3];
  }
}

// ---- rank: computes its own exclusive block offset from cnt[] (no scan
// kernel on the critical path; <=391 L2-hit ints summed in parallel) ------
__global__ __launch_bounds__(256) void rank_kernel(const int* __restrict__ ch,
                                                   const int* __restrict__ cnt, int n,
                                                   int* __restrict__ rowof,
                                                   int* __restrict__ leafof) {
  int tid = threadIdx.x;
  int lane = tid & 63, w = tid >> 6;

  // exclusive prefix of leaf counts over blocks [0, blockIdx.x)
  int pre = 0;
  for (int i = tid; i < (int)blockIdx.x; i += 256) pre += cnt[i];
#pragma unroll
  for (int o = 32; o > 0; o >>= 1) pre += __shfl_down(pre, o);
  __shared__ int ws4[4];
  if (lane == 0) ws4[w] = pre;

  int gi = blockIdx.x * 256 + tid;
  int lm = (gi < n && ch[gi] < 0) ? 1 : 0;
  unsigned long long mask = __ballot(lm);
  int lrank = __popcll(mask & ((1ull << lane) - 1ull));
  __shared__ int wcnt[4];
  if (lane == 63) wcnt[w] = lrank + lm;
  __syncthreads();
  int boffv = ws4[0] + ws4[1] + ws4[2] + ws4[3];
  int woff = 0;
  for (int i = 0; i < w; ++i) woff += wcnt[i];
  if (gi < n) {
    int rl = boffv + woff + lrank;     // leaves strictly before gi
    if (lm) leafof[rl] = gi;
    else    rowof[gi - rl] = gi;
  }
}

// ---- main: GEMM tiles (blocks < TILES) + grid-stride row copies ----------
// Round-12 champion, unchanged: BM=64, BN=256(full), BK=128; 256 thr =
// 4 waves (N-split), 2 blk/CU; A via global_load_lds NT (XOR-swizzled
// source + swizzled frag read), dbuf, counted vmcnt(8), raw barriers,
// per-block K-phase rotation; B direct from L2-resident bf16 W; NT
// copy path + NT epilogue stores.
__global__ __launch_bounds__(256, 2) void main_kernel(const float* __restrict__ x,
                                                      const float* __restrict__ A,
                                                      const unsigned short* __restrict__ Wb,
                                                      const int* __restrict__ rowof,
                                                      const int* __restrict__ leafof,
                                                      float* __restrict__ out) {
  __shared__ float Al[2][BM][BKF];     // 2 x 32KB
  __shared__ int tgt[BM];

  const int tid  = threadIdx.x;
  const int lane = tid & 63;
  const int w    = tid >> 6;

  if (blockIdx.x >= TILES) {                      // ---- copy path ----
    int cb = blockIdx.x - TILES;
    for (int r0 = cb * 4; r0 < COPYROWS; r0 += NCOPYB * 4) {
      int j = r0 + w;
      if (j >= COPYROWS) break;
      const float* src;
      float* dst;
      if (j < PREFIX_N) {
        src = x + (size_t)j * CCOL;
        dst = out + (size_t)j * CCOL;
      } else {
        int r = j - PREFIX_N;
        src = x + (size_t)(PREFIX_N + r) * CCOL;
        dst = out + (size_t)(PREFIX_N + leafof[r]) * CCOL;
      }
      f32x4v v = __builtin_nontemporal_load((const f32x4v*)src + lane);
      __builtin_nontemporal_store(v, (f32x4v*)dst + lane);
    }
    return;
  }

  // ---- GEMM path ----
  const int tile  = blockIdx.x;
  const int phase = tile & (NST - 1);
  const int wn    = w;                 // wave's N-quadrant
  const int lr    = lane & 15, lq = lane >> 4;

  if (tid < BM) {
    int m = tile * BM + tid;
    tgt[tid] = (m < GM) ? (PREFIX_N + rowof[m]) : -1;
  }

  // glds i covers rows w*16+2i (+1 for lanes>=32); source chunk pre-swizzled
  const float* asrc[8];
  int myrow = w * 16 + (lane >> 5);
#pragma unroll
  for (int i = 0; i < 8; ++i) {
    int r  = myrow + 2 * i;            // this lane's global A-row for glds i
    int gr = tile * BM + r;
    if (gr >= GM) gr = GM - 1;         // clamp (epilogue predicated)
    int chunk = (lane & 31) ^ (r & 7); // inverse swizzle on SOURCE
    asrc[i] = A + (size_t)gr * GK + chunk * 4;
  }

  // B fragment base pointers (global; Wb 1MB, L2-resident)
  const unsigned short* bb[4];
#pragma unroll
  for (int fn = 0; fn < 4; ++fn)
    bb[fn] = Wb + (size_t)(wn * 64 + fn * 16 + lr) * GK + lq * 8;

  f32x4v acc[4][4] = {};

#define ISSUE_A(kc_, buf_)                                                   \
  { _Pragma("unroll") for (int i = 0; i < 8; ++i)                            \
      GLDS16NT(asrc[i] + (kc_) * BKF, (char*)&Al[(buf_)][w * 16 + 2 * i][0]); }

  {
    int kc0 = phase;
    int kc1 = (phase + 1) & (NST - 1);
    ISSUE_A(kc0, 0);
    ISSUE_A(kc1, 1);
  }

#pragma unroll 1
  for (int kt = 0; kt < NST; ++kt) {
    int kc = phase + kt; if (kc >= NST) kc -= NST;   // rotated K-chunk
    if (kt < NST - 1) { asm volatile("s_waitcnt vmcnt(8)" ::: "memory"); }
    else              { asm volatile("s_waitcnt vmcnt(0)" ::: "memory"); }
    __builtin_amdgcn_s_barrier();      // buf kt fully staged (all waves)

    const float* Ab = &Al[kt & 1][0][0];
#pragma unroll
    for (int ks = 0; ks < 4; ++ks) {
      s16x8 af[4], bf[4];
#pragma unroll
      for (int fm = 0; fm < 4; ++fm) {
        int row = fm * 16 + lr;
        int e   = ks * 8 + lq * 2;
        int p0  = ((e)     ^ (row & 7)) << 2;   // swizzled read
        int p1  = ((e + 1) ^ (row & 7)) << 2;
        float4 u0 = *(const float4*)&Ab[row * BKF + p0];
        float4 u1 = *(const float4*)&Ab[row * BKF + p1];
        af[fm] = __builtin_bit_cast(s16x8, pack8(u0, u1));
      }
#pragma unroll
      for (int fn = 0; fn < 4; ++fn)
        bf[fn] = *(const s16x8*)&bb[fn][kc * BKF + ks * 32];
#pragma unroll
      for (int fm = 0; fm < 4; ++fm)
#pragma unroll
        for (int fn = 0; fn < 4; ++fn)
          acc[fm][fn] = __builtin_amdgcn_mfma_f32_16x16x32_bf16(
              __builtin_bit_cast(bf16x8, af[fm]),
              __builtin_bit_cast(bf16x8, bf[fn]),
              acc[fm][fn], 0, 0, 0);
    }

    asm volatile("s_waitcnt lgkmcnt(0)" ::: "memory");  // ds_reads of buf kt done
    __builtin_amdgcn_s_barrier();                       // safe to overwrite
    if (kt + 2 < NST) {
      int kc2 = phase + kt + 2; if (kc2 >= NST) kc2 -= NST;
      ISSUE_A(kc2, kt & 1);                             // refill just-read buffer
    }
  }
#undef ISSUE_A

  // ---- epilogue: scatter rows (C/D: col=lane&15, row=(lane>>4)*4+reg) ----
#pragma unroll
  for (int fm = 0; fm < 4; ++fm) {
    int mlb = fm * 16 + lq * 4;
    int t0 = tgt[mlb + 0], t1 = tgt[mlb + 1], t2 = tgt[mlb + 2], t3 = tgt[mlb + 3];
#pragma unroll
    for (int fn = 0; fn < 4; ++fn) {
      int col = wn * 64 + fn * 16 + lr;
      if (t0 >= 0) __builtin_nontemporal_store(acc[fm][fn][0], &out[(size_t)t0 * CCOL + col]);
      if (t1 >= 0) __builtin_nontemporal_store(acc[fm][fn][1], &out[(size_t)t1 * CCOL + col]);
      if (t2 >= 0) __builtin_nontemporal_store(acc[fm][fn][2], &out[(size_t)t2 * CCOL + col]);
      if (t3 >= 0) __builtin_nontemporal_store(acc[fm][fn][3], &out[(size_t)t3 * CCOL + col]);
    }
  }
}

extern "C" void kernel_launch(void* const* d_in, const int* in_sizes, int n_in,
                              void* d_out, int out_size, void* d_ws, size_t ws_size,
                              hipStream_t stream) {
  const float* x        = (const float*)d_in[0];
  const float* wts      = (const float*)d_in[1];   // (256,256,8) == row-major (256,2048)
  const int*   children = (const int*)d_in[2];
  float*       out      = (float*)d_out;

  int* wsp    = (int*)d_ws;
  int* cnt    = wsp;                 // 391
  int* rowof  = wsp + 1024;          // 50000
  int* leafof = wsp + 1024 + GM;     // 50000
  unsigned short* Wb = (unsigned short*)((char*)d_ws + (1 << 20));  // 1 MB bf16 W

  const int nb = (CH_N + 255) / 256;   // 391

  prep_kernel<<<256 + nb, 256, 0, stream>>>(wts, Wb, children, cnt);
  rank_kernel<<<nb, 256, 0, stream>>>(children, cnt, CH_N, rowof, leafof);

  const float* A = x + (size_t)(PREFIX_N + LEAF_N) * CCOL;
  main_kernel<<<TILES + NCOPYB, 256, 0, stream>>>(x, A, Wb, rowof, leafof, out);
}